// Round 1
// baseline (295.112 us; speedup 1.0000x reference)
//
#include <hip/hip_runtime.h>
#include <hip/hip_fp16.h>
#include <math.h>

#define T_DIM 2048
#define K_DIM 17
#define HID   64
#define B_DIM 32

typedef short s16x8 __attribute__((ext_vector_type(8)));
typedef unsigned u32x2 __attribute__((ext_vector_type(2)));
typedef float f32x4 __attribute__((ext_vector_type(4)));
typedef _Float16 f16x2 __attribute__((ext_vector_type(2)));

// packed f32 pair -> f16 pair (1 instruction: v_cvt_pkrtz_f16_f32)
__device__ __forceinline__ unsigned pkh(float lo, float hi) {
    return __builtin_bit_cast(unsigned, __builtin_amdgcn_cvt_pkrtz(lo, hi));
}
__device__ __forceinline__ f16x2 u2h(unsigned v) {
    return __builtin_bit_cast(f16x2, v);
}
__device__ __forceinline__ unsigned h2u(f16x2 v) {
    return __builtin_bit_cast(unsigned, v);
}
__device__ __forceinline__ short f2h(float f) {          // cold path
    _Float16 h = (_Float16)f;
    return __builtin_bit_cast(short, h);
}

// COCO skeleton sparsity: column-v nonzeros of adj (incl. self).
static constexpr int NBR_PTR[18] = {0,3,6,9,11,13,17,21,24,27,29,31,34,37,40,43,45,47};
static constexpr int NBR_K[47] = {
    0,1,2,  0,1,3,  0,2,4,  1,3,  2,4,
    5,6,7,11,  5,6,8,12,  5,7,9,  6,8,10,  7,9,  8,10,
    5,11,13,  6,12,14,  11,13,15,  12,14,16,  13,15,  14,16 };
__device__ const int d_NBR_PTR[18] = {0,3,6,9,11,13,17,21,24,27,29,31,34,37,40,43,45,47};
__device__ const int d_NBR_K[47] = {
    0,1,2,  0,1,3,  0,2,4,  1,3,  2,4,
    5,6,7,11,  5,6,8,12,  5,7,9,  6,8,10,  7,9,  8,10,
    5,11,13,  6,12,14,  11,13,15,  12,14,16,  13,15,  14,16 };

// ---------------------------------------------------------------------------
// Fold GCN channel-mix into temporal conv weights (f16).
//   effT0[o][k32]  k = dt*8+cin (cin<3, dt<3), rest 0    (block1, K=32)
//   effT12[blk][o][dt*64+c]                              (blocks 2,3, K=192)
//   bnc[blk*64+o] = s/sqrt(v+eps);  bnc[192+blk*64+o] = b - m*inv
// ---------------------------------------------------------------------------
__global__ void fold_weights_kernel(
    const float* __restrict__ gw0, const float* __restrict__ gw1,
    const float* __restrict__ gw2, const float* __restrict__ tcn,
    const float* __restrict__ bns, const float* __restrict__ bnb,
    const float* __restrict__ bnm, const float* __restrict__ bnv,
    short* __restrict__ effT0, short* __restrict__ effT12,
    float* __restrict__ bnc)
{
    int tid = blockIdx.x * blockDim.x + threadIdx.x;
    int stride = gridDim.x * blockDim.x;
    for (int idx = tid; idx < 2048; idx += stride) {
        int o = idx >> 5, k = idx & 31, dt = k >> 3, cin = k & 7;
        float s = 0.f;
        if (dt < 3 && cin < 3)
            for (int m = 0; m < 64; m++)
                s += gw0[cin * 64 + m] * tcn[(o * 64 + m) * 3 + dt];
        effT0[idx] = f2h(s);
    }
    for (int idx = tid; idx < 24576; idx += stride) {
        int blk = idx / 12288;
        int r = idx - blk * 12288;
        int o = r / 192, k = r - o * 192, dt = k >> 6, c = k & 63;
        const float* gw = blk ? gw2 : gw1;
        const float* tw = tcn + (size_t)(blk + 1) * 64 * 64 * 3;
        float s = 0.f;
        for (int m = 0; m < 64; m++)
            s += gw[c * 64 + m] * tw[(o * 64 + m) * 3 + dt];
        effT12[idx] = f2h(s);
    }
    for (int i = tid; i < 192; i += stride) {
        float inv = bns[i] * rsqrtf(bnv[i] + 1e-5f);
        bnc[i] = inv;
        bnc[192 + i] = bnb[i] - bnm[i] * inv;
    }
}

// ---------------------------------------------------------------------------
// Fully fused kernel: premix + block1 + block2 + block3 + pool, all in LDS.
// Per block: 8 output t-rows.  Halo recompute: y2 over 12 t-rows (204 kpt
// rows), y1 over 14 t-rows (238 rows), x over 16 t-rows.
//   GEMM1: 15 tiles K=32  -> y1buf (BN+ReLU, t-valid zeroing)
//   GEMM2: 13 tiles K=192 streaming -> z2 in y2buf; mix2 in-place + y1
//          residual + invalid-t zeroing -> y2buf
//   GEMM3: 9 tiles K=192 dil=2 streaming -> z3 in y1buf (dead);
//          mix3 + residual-presum + pool -> part
// LDS 72.5 KB -> 2 blocks/CU.
// ---------------------------------------------------------------------------
__global__ __launch_bounds__(256, 2) void stgcn_fused_kernel(
    const float* __restrict__ x, const float* __restrict__ adj,
    const short* __restrict__ effT0, const short* __restrict__ effT12,
    const short* __restrict__ effW3, const float* __restrict__ bnc,
    float* __restrict__ part)
{
    __shared__ unsigned adj_h[289];                    // f16x2 broadcast pairs
    __shared__ float adj_f[289];
    __shared__ __align__(16) float xs[16 * 51];        // raw x rows t0-4..t0+11
    __shared__ __align__(16) float xtg[16 * 52];       // premixed
    __shared__ __align__(16) short y1buf[238 * 72];    // 34272 B
    __shared__ __align__(16) short y2buf[204 * 72];    // 29376 B
    float* const pr = xs;                              // pool partials alias

    const int tid = threadIdx.x;
    const int b = blockIdx.y;
    const int t0 = blockIdx.x * 8;
    const int lane = tid & 63, wave = tid >> 6;
    const int col = lane & 15, kgrp = lane >> 4;

    for (int i = tid; i < 289; i += 256) {
        float w = adj[i];
        adj_f[i] = w;
        adj_h[i] = pkh(w, w);
    }
    {   // coalesced stage of raw x rows t = t0-4 .. t0+11 (zero for OOB t)
        const float* src = x + ((size_t)b * T_DIM + t0 - 4) * 51;
        for (int i = tid; i < 816; i += 256) {
            const int row = i / 51;
            const int t = t0 - 4 + row;
            xs[i] = (t >= 0 && t < T_DIM) ? src[i] : 0.f;
        }
    }
    // weight A-frags (m-tile per wave: o = wave*16 + col)
    s16x8 af1 = *(const s16x8*)(effT0 + (wave * 16 + col) * 32 + kgrp * 8);
    s16x8 af2[6];
    #pragma unroll
    for (int kk = 0; kk < 6; kk++)
        af2[kk] = *(const s16x8*)(effT12 +
            (wave * 16 + col) * 192 + kk * 32 + kgrp * 8);
    __syncthreads();

    // ---- premix: xtg[r][j*3+c] = sum_k adj[k][j] * xs[r][k*3+c] ----
    for (int i = tid; i < 272; i += 256) {
        const int r = (i * 241) >> 12;                 // i/17
        const int j = i - r * 17;
        const float* xp = &xs[r * 51];
        float a0 = 0.f, a1 = 0.f, a2 = 0.f;
        const int p0 = d_NBR_PTR[j], p1 = d_NBR_PTR[j + 1];
        for (int e = p0; e < p1; e++) {
            const int k = d_NBR_K[e];
            const float w = adj_f[k * 17 + j];
            a0 += w * xp[k * 3 + 0];
            a1 += w * xp[k * 3 + 1];
            a2 += w * xp[k * 3 + 2];
        }
        float* op = &xtg[r * 52 + j * 3];
        op[0] = a0; op[1] = a1; op[2] = a2;
    }
    __syncthreads();

    // ---- GEMM1: 238 rows (15 tiles), K=32; epilogue BN+ReLU (+t-valid
    //      zeroing) -> y1 rows (t = t0-3 .. t0+10) ----
    {
        f32x4 inv4 = *(const f32x4*)&bnc[wave * 16 + kgrp * 4];
        f32x4 sh4  = *(const f32x4*)&bnc[192 + wave * 16 + kgrp * 4];
        for (int tile = 0; tile < 15; tile++) {
            const int r = tile * 16 + col;
            const int me = r < 238 ? r : 237;
            const int s = (me * 241) >> 12;            // me/17
            const int j = me - s * 17;
            int4 bz = {0, 0, 0, 0};
            if (kgrp < 3) {                            // dt = kgrp
                const float* xp = &xtg[(s + kgrp) * 52 + j * 3];
                bz.x = (int)pkh(xp[0], xp[1]);
                bz.y = (int)pkh(xp[2], 0.f);
            }
            s16x8 bfr = __builtin_bit_cast(s16x8, bz);
            f32x4 acc = __builtin_amdgcn_mfma_f32_16x16x32_f16(
                af1, bfr, (f32x4){0.f, 0.f, 0.f, 0.f}, 0, 0, 0);
            const int t = t0 - 3 + s;
            const bool valid = (t >= 0) && (t < T_DIM);
            if (r < 238) {
                float v0 = valid ? fmaxf(acc[0] * inv4[0] + sh4[0], 0.f) : 0.f;
                float v1 = valid ? fmaxf(acc[1] * inv4[1] + sh4[1], 0.f) : 0.f;
                float v2 = valid ? fmaxf(acc[2] * inv4[2] + sh4[2], 0.f) : 0.f;
                float v3 = valid ? fmaxf(acc[3] * inv4[3] + sh4[3], 0.f) : 0.f;
                u32x2 st; st[0] = pkh(v0, v1); st[1] = pkh(v2, v3);
                *(u32x2*)&y1buf[r * 72 + wave * 16 + kgrp * 4] = st;
            }
        }
    }
    __syncthreads();

    // ---- GEMM2: 204 rows (13 tiles), K=192, streaming -> z2 in y2buf ----
    for (int t2 = 0; t2 < 13; t2++) {
        const int r = t2 * 16 + col;
        const int me = r < 204 ? r : 203;
        f32x4 acc = {0.f, 0.f, 0.f, 0.f};
        #pragma unroll
        for (int kk = 0; kk < 6; kk++) {
            s16x8 bfr = *(const s16x8*)&y1buf[
                (me + 17 * (kk >> 1)) * 72 + (kk & 1) * 32 + kgrp * 8];
            acc = __builtin_amdgcn_mfma_f32_16x16x32_f16(af2[kk], bfr, acc, 0, 0, 0);
        }
        if (r < 204) {
            u32x2 st;
            st[0] = pkh(acc[0], acc[1]);
            st[1] = pkh(acc[2], acc[3]);
            *(u32x2*)&y2buf[r * 72 + wave * 16 + kgrp * 4] = st;
        }
    }
    // load block-3 A-frags now (af2 dead after this point)
    s16x8 af3[6];
    #pragma unroll
    for (int kk = 0; kk < 6; kk++)
        af3[kk] = *(const s16x8*)(effW3 +
            (wave * 16 + col) * 192 + kk * 32 + kgrp * 8);
    __syncthreads();

    // ---- mix2 (packed f16) in-place on y2buf + y1 residual + invalid-t
    //      zeroing.  Each item (tl,o0) reads exactly the cells it writes. ----
    {
        const f16x2 zero = u2h(0u);
        for (int i = tid; i < 384; i += 256) {
            const int tl = i >> 5, o0 = (i & 31) * 2;
            const f16x2 inv2 = u2h(pkh(bnc[64 + o0], bnc[64 + o0 + 1]));
            const f16x2 sh2  = u2h(pkh(bnc[256 + o0], bnc[256 + o0 + 1]));
            f16x2 zk[17];
            #pragma unroll
            for (int k = 0; k < 17; k++)
                zk[k] = u2h(*(const unsigned*)&y2buf[(tl * 17 + k) * 72 + o0]);
            const int t = t0 - 2 + tl;
            const bool valid = (t >= 0) && (t < T_DIM);
            #pragma unroll
            for (int v = 0; v < 17; v++) {
                f16x2 g = zero;
                #pragma unroll
                for (int e = NBR_PTR[v]; e < NBR_PTR[v + 1]; e++) {
                    int k = NBR_K[e];
                    g = u2h(adj_h[k * 17 + v]) * zk[k] + g;
                }
                f16x2 val = __builtin_elementwise_max(g * inv2 + sh2, zero);
                val = val + u2h(*(const unsigned*)&y1buf[
                    ((tl + 1) * 17 + v) * 72 + o0]);
                *(unsigned*)&y2buf[(tl * 17 + v) * 72 + o0] =
                    valid ? h2u(val) : 0u;
            }
        }
    }
    __syncthreads();

    // ---- residual/pool pre-sum over y2 rows t0..t0+7 (before overwrite) ----
    f16x2 rs = u2h(0u);
    {
        const int tl = tid >> 5, o0 = (tid & 31) * 2;
        #pragma unroll
        for (int v = 0; v < 17; v++)
            rs = rs + u2h(*(const unsigned*)&y2buf[((tl + 2) * 17 + v) * 72 + o0]);
    }

    // ---- GEMM3: 136 rows (9 tiles), K=192, DIL=2, streaming -> z3 in y1buf ----
    for (int t3 = 0; t3 < 9; t3++) {
        const int r = t3 * 16 + col;
        const int me = r < 136 ? r : 135;
        f32x4 acc = {0.f, 0.f, 0.f, 0.f};
        #pragma unroll
        for (int kk = 0; kk < 6; kk++) {
            s16x8 bfr = *(const s16x8*)&y2buf[
                (me + 34 * (kk >> 1)) * 72 + (kk & 1) * 32 + kgrp * 8];
            acc = __builtin_amdgcn_mfma_f32_16x16x32_f16(af3[kk], bfr, acc, 0, 0, 0);
        }
        if (r < 136) {
            u32x2 st;
            st[0] = pkh(acc[0], acc[1]);
            st[1] = pkh(acc[2], acc[3]);
            *(u32x2*)&y1buf[r * 72 + wave * 16 + kgrp * 4] = st;
        }
    }
    __syncthreads();

    // ---- mix3 (packed f16) + pool ----
    {
        const int tl = tid >> 5, o0 = (tid & 31) * 2;
        const f16x2 inv2 = u2h(pkh(bnc[128 + o0], bnc[128 + o0 + 1]));
        const f16x2 sh2  = u2h(pkh(bnc[320 + o0], bnc[320 + o0 + 1]));
        const f16x2 zero = u2h(0u);
        f16x2 zk[17];
        #pragma unroll
        for (int k = 0; k < 17; k++)
            zk[k] = u2h(*(const unsigned*)&y1buf[(tl * 17 + k) * 72 + o0]);
        float ps0 = (float)rs[0], ps1 = (float)rs[1];
        #pragma unroll
        for (int v = 0; v < 17; v++) {
            f16x2 g = zero;
            #pragma unroll
            for (int e = NBR_PTR[v]; e < NBR_PTR[v + 1]; e++) {
                int k = NBR_K[e];
                g = u2h(adj_h[k * 17 + v]) * zk[k] + g;
            }
            f16x2 val = __builtin_elementwise_max(g * inv2 + sh2, zero);
            ps0 += (float)val[0];
            ps1 += (float)val[1];
        }
        *(float2*)&pr[tl * 64 + o0] = make_float2(ps0, ps1);
    }
    __syncthreads();
    if (tid < 64) {
        float s = 0.f;
        #pragma unroll
        for (int i = 0; i < 8; i++) s += pr[i * 64 + tid];
        part[((size_t)b * 256 + blockIdx.x) * 64 + tid] = s;
    }
}

// ---------------------------------------------------------------------------
// Sum 256 partials per (b,c) with 256 threads, mean, LayerNorm, FC.
// ---------------------------------------------------------------------------
__global__ __launch_bounds__(256) void finish_kernel(
    const float* __restrict__ part, const float* __restrict__ ln_s,
    const float* __restrict__ ln_b, const float* __restrict__ fc_w,
    const float* __restrict__ fc_b, float* __restrict__ out)
{
    __shared__ float red[4][64];
    __shared__ float ns[64];
    const int b = blockIdx.x;
    const int g = threadIdx.x >> 6, c = threadIdx.x & 63;
    float s = 0.f;
    for (int j = 0; j < 64; j++)
        s += part[((size_t)b * 256 + g * 64 + j) * 64 + c];
    red[g][c] = s;
    __syncthreads();
    if (threadIdx.x < 64) {
        float feat = (red[0][c] + red[1][c] + red[2][c] + red[3][c])
                   / (float)(T_DIM * K_DIM);
        float m = feat;
        #pragma unroll
        for (int off = 32; off > 0; off >>= 1) m += __shfl_down(m, off);
        m = __shfl(m, 0) / 64.f;
        float d = feat - m;
        float v = d * d;
        #pragma unroll
        for (int off = 32; off > 0; off >>= 1) v += __shfl_down(v, off);
        v = __shfl(v, 0) / 64.f;
        ns[c] = d * rsqrtf(v + 1e-5f) * ln_s[c] + ln_b[c];
    }
    __syncthreads();
    if (threadIdx.x < 10) {
        float o = fc_b[threadIdx.x];
        for (int i = 0; i < 64; i++) o += ns[i] * fc_w[i * 10 + threadIdx.x];
        out[b * 10 + threadIdx.x] = o;
    }
}

// ---------------------------------------------------------------------------
extern "C" void kernel_launch(void* const* d_in, const int* in_sizes, int n_in,
                              void* d_out, int out_size, void* d_ws, size_t ws_size,
                              hipStream_t stream)
{
    const float* kpts = (const float*)d_in[0];
    const float* adj  = (const float*)d_in[1];
    const float* gw0  = (const float*)d_in[2];
    const float* gw1  = (const float*)d_in[3];
    const float* gw2  = (const float*)d_in[4];
    const float* tcn  = (const float*)d_in[5];
    const float* bns  = (const float*)d_in[6];
    const float* bnb  = (const float*)d_in[7];
    const float* bnm  = (const float*)d_in[8];
    const float* bnv  = (const float*)d_in[9];
    const float* lns  = (const float*)d_in[10];
    const float* lnb  = (const float*)d_in[11];
    const float* fcw  = (const float*)d_in[12];
    const float* fcb  = (const float*)d_in[13];
    float* out = (float*)d_out;

    // ws: bnc | part | effT0 | effT12  (~2.1 MB total)
    float* bnc  = (float*)d_ws;
    float* part = bnc + 384;
    short* effT0  = (short*)(part + (size_t)B_DIM * 256 * 64);
    short* effT12 = effT0 + 2048;

    fold_weights_kernel<<<64, 256, 0, stream>>>(gw0, gw1, gw2, tcn,
                                                bns, bnb, bnm, bnv,
                                                effT0, effT12, bnc);

    stgcn_fused_kernel<<<dim3(T_DIM / 8, B_DIM), 256, 0, stream>>>(
        kpts, adj, effT0, effT12, effT12 + 12288, bnc, part);

    finish_kernel<<<B_DIM, 256, 0, stream>>>(part, lns, lnb, fcw, fcb, out);
}